// Round 6
// baseline (223.543 us; speedup 1.0000x reference)
//
#include <hip/hip_runtime.h>
#include <hip/hip_bf16.h>

#define B_ 8
#define C_ 2048
#define DIM_ 512
#define NEG_SLOPE 0.01f

typedef short bf16x8 __attribute__((ext_vector_type(8)));
typedef float f32x4 __attribute__((ext_vector_type(4)));

// ---- workspace byte offsets
#define WT_OFF   0                        // bf16 Wt[512][512] (W_comb^T)
#define UT_OFF   524288                   // bf16 Ut[8*512][2048]  (U^T per batch)
#define FP_OFF   (524288 + 16777216)      // fp32 region
// ---- float offsets inside fp32 region
#define BCOMB_F  0
#define WQ_F     512
#define WK_F     1024
#define CQB_F    1536
#define CK_F     1537
#define SQP_F    2048
#define SKP_F    18432

static __device__ __forceinline__ unsigned short bf16u(float x) {
    union { __hip_bfloat16 h; unsigned short u; } c;
    c.h = __float2bfloat16(x);
    return c.u;
}

// wq_vec[e] = sum_h W_w[e,h]*a[h]; wk_vec[e] = sum_h W_w[e,512+h]*a[512+h]
__global__ void k_prep_wqk(const float* __restrict__ W_w, const float* __restrict__ a_score, float* wsf) {
    int wave = threadIdx.x >> 6, lane = threadIdx.x & 63;
    int e = blockIdx.x * 4 + wave;
    const float4* R4 = (const float4*)(W_w + (size_t)e * 1536);
    const float4* A4 = (const float4*)a_score;
    float aq = 0.f, ak = 0.f;
#pragma unroll
    for (int k = 0; k < 2; ++k) {
        float4 f = R4[lane + 64 * k];
        float4 a = A4[lane + 64 * k];
        aq += f.x * a.x + f.y * a.y + f.z * a.z + f.w * a.w;
        float4 g = R4[128 + lane + 64 * k];
        float4 a2 = A4[128 + lane + 64 * k];
        ak += g.x * a2.x + g.y * a2.y + g.z * a2.z + g.w * a2.w;
    }
#pragma unroll
    for (int off = 32; off; off >>= 1) { aq += __shfl_xor(aq, off); ak += __shfl_xor(ak, off); }
    if (lane == 0) { wsf[WQ_F + e] = aq; wsf[WK_F + e] = ak; }
}

__global__ void k_prep_cqk(const float* __restrict__ b_w, const float* __restrict__ a_score,
                           const float* __restrict__ b_score, float* wsf) {
    __shared__ float s1[512], s2[512];
    int t = threadIdx.x;
    s1[t] = b_w[t] * a_score[t];
    s2[t] = b_w[512 + t] * a_score[512 + t];
    __syncthreads();
    for (int off = 256; off > 0; off >>= 1) {
        if (t < off) { s1[t] += s1[t + off]; s2[t] += s2[t + off]; }
        __syncthreads();
    }
    if (t == 0) { wsf[CQB_F] = s1[0] + b_score[0]; wsf[CK_F] = s2[0]; }
}

// Wt[d][e] = sum_h W_w[e,1024+h]*W_out[h,d]; bcomb[d] = sum_h b_w[1024+h]*W_out[h,d]
__global__ __launch_bounds__(256) void k_wt(const float* __restrict__ W_w,
                                            const float* __restrict__ W_out,
                                            const float* __restrict__ b_w,
                                            char* wsb, float* wsf) {
    __shared__ float As[32][34];
    __shared__ float Bs[32][34];
    const int t = threadIdx.x;
    const int d0 = (blockIdx.x & 15) * 32;
    const int e0 = (blockIdx.x >> 4) * 32;
    const int ty = t >> 4, tx = t & 15;
    const int hl = t >> 5, c = t & 31;
    float a00 = 0.f, a01 = 0.f, a10 = 0.f, a11 = 0.f;
    float bc = 0.f;
    for (int k0 = 0; k0 < 512; k0 += 32) {
#pragma unroll
        for (int r = 0; r < 4; ++r) {
            int h = hl + 8 * r;
            As[h][c] = W_out[(size_t)(k0 + h) * 512 + d0 + c];
            Bs[c][h] = W_w[(size_t)(e0 + h) * 1536 + 1024 + k0 + c];
        }
        __syncthreads();
        if (e0 == 0 && t < 32) {
#pragma unroll
            for (int kk = 0; kk < 32; ++kk)
                bc = fmaf(b_w[1024 + k0 + kk], As[kk][t], bc);
        }
#pragma unroll
        for (int kk = 0; kk < 32; ++kk) {
            float2 a2 = *(const float2*)&As[kk][ty * 2];
            float2 b2 = *(const float2*)&Bs[kk][tx * 2];
            a00 = fmaf(a2.x, b2.x, a00);
            a01 = fmaf(a2.x, b2.y, a01);
            a10 = fmaf(a2.y, b2.x, a10);
            a11 = fmaf(a2.y, b2.y, a11);
        }
        __syncthreads();
    }
    unsigned short* Wt = (unsigned short*)(wsb + WT_OFF);
    const int d = d0 + ty * 2, e = e0 + tx * 2;
    Wt[(size_t)d * 512 + e]           = bf16u(a00);
    Wt[(size_t)d * 512 + e + 1]       = bf16u(a01);
    Wt[(size_t)(d + 1) * 512 + e]     = bf16u(a10);
    Wt[(size_t)(d + 1) * 512 + e + 1] = bf16u(a11);
    if (e0 == 0 && t < 32) wsf[BCOMB_F + d0 + t] = bc;
}

// sq'[n], sk'[n]
__global__ void k_sqsk(const float* __restrict__ feat, float* wsf) {
    int wave = threadIdx.x >> 6, lane = threadIdx.x & 63;
    int n = blockIdx.x * 4 + wave;
    const float4* F4 = (const float4*)(feat + (size_t)n * 512);
    const float4* WQ4 = (const float4*)(wsf + WQ_F);
    const float4* WK4 = (const float4*)(wsf + WK_F);
    float aq = 0.f, ak = 0.f;
#pragma unroll
    for (int k = 0; k < 2; ++k) {
        float4 f = F4[lane + 64 * k];
        float4 q = WQ4[lane + 64 * k];
        float4 kk = WK4[lane + 64 * k];
        aq += f.x * q.x + f.y * q.y + f.z * q.z + f.w * q.w;
        ak += f.x * kk.x + f.y * kk.y + f.z * kk.z + f.w * kk.w;
    }
#pragma unroll
    for (int off = 32; off; off >>= 1) { aq += __shfl_xor(aq, off); ak += __shfl_xor(ak, off); }
    if (lane == 0) {
        wsf[SQP_F + n] = aq + wsf[CQB_F];
        wsf[SKP_F + n] = ak + wsf[CK_F];
    }
}

// Ut[b,d,j] = sum_e Wt[d,e] * F[b,j,e]   (512 blocks: j-tile 32, 4 waves x 128 d)
__global__ __launch_bounds__(256) void k_ut(const float* __restrict__ F, char* __restrict__ wsb) {
    __shared__ unsigned short Fb[32][520];
    const int t = threadIdx.x;
    const int bid = blockIdx.x;
    const int b = bid & 7, j0 = (bid >> 3) * 32;
    const unsigned short* Wt = (const unsigned short*)(wsb + WT_OFF);
    unsigned short* Ut = (unsigned short*)(wsb + UT_OFF) + (size_t)b * 512 * 2048;
    const float* Ft = F + ((size_t)(b * C_ + j0)) * 512;
#pragma unroll
    for (int q = 0; q < 16; ++q) {
        float4 v = *(const float4*)(Ft + (size_t)q * 1024 + t * 4);
        int jr = 2 * q + (t >> 7);
        int e = (t & 127) * 4;
        unsigned int lo = (unsigned int)bf16u(v.x) | ((unsigned int)bf16u(v.y) << 16);
        unsigned int hi = (unsigned int)bf16u(v.z) | ((unsigned int)bf16u(v.w) << 16);
        *(uint2*)&Fb[jr][e] = make_uint2(lo, hi);
    }
    __syncthreads();
    const int l = t & 63, lr = l & 15, lg = l >> 4;
    const int d0 = (t >> 6) * 128;
    f32x4 acc[8][2];
#pragma unroll
    for (int m = 0; m < 8; ++m)
#pragma unroll
        for (int n = 0; n < 2; ++n) acc[m][n] = (f32x4){0.f, 0.f, 0.f, 0.f};
#pragma unroll
    for (int ks = 0; ks < 16; ++ks) {
        bf16x8 af[8], bv[2];
#pragma unroll
        for (int m = 0; m < 8; ++m)
            af[m] = *(const bf16x8*)(Wt + (size_t)(d0 + 16 * m + lr) * 512 + ks * 32 + 8 * lg);
#pragma unroll
        for (int n = 0; n < 2; ++n)
            bv[n] = *(const bf16x8*)&Fb[16 * n + lr][ks * 32 + 8 * lg];
#pragma unroll
        for (int m = 0; m < 8; ++m)
#pragma unroll
            for (int n = 0; n < 2; ++n)
                acc[m][n] = __builtin_amdgcn_mfma_f32_16x16x32_bf16(af[m], bv[n], acc[m][n], 0, 0, 0);
    }
#pragma unroll
    for (int m = 0; m < 8; ++m)
#pragma unroll
        for (int n = 0; n < 2; ++n)
#pragma unroll
            for (int r = 0; r < 4; ++r) {
                int d = d0 + 16 * m + lg * 4 + r;
                int j = j0 + 16 * n + lr;
                Ut[(size_t)d * 2048 + j] = bf16u(acc[m][n][r]);
            }
}

// fused attention: 512 blocks x 256 thr (4 waves); 32 i-rows/block; 2 blocks/CU.
// Main-loop barriers: lgkmcnt-only (NO vmcnt drain) so mask prefetches stay in flight.
#define BAR asm volatile("s_waitcnt lgkmcnt(0)\n\ts_barrier" ::: "memory");

#define ISSUE(S, KT) { \
    mk##S##a = __builtin_nontemporal_load((const f32x4*)(mrowp + (KT) * 64)); \
    mk##S##b = __builtin_nontemporal_load((const f32x4*)(mrowp + (KT) * 64 + 4)); }

#define PC1(ZS, MKC, VI) { \
    float z = sqv + (ZS); z = fmaxf(z, z * NEG_SLOPE) * (MKC); \
    float p = __expf(z); psum += p; vv[VI] = (short)bf16u(p); }

#define PCOMP(S, BUF, KT) { \
    float4 ska = *(const float4*)&sk_lds[(KT) * 64 + jc * 8]; \
    float4 skc = *(const float4*)&sk_lds[(KT) * 64 + jc * 8 + 4]; \
    bf16x8 vv; \
    PC1(ska.x, mk##S##a.x, 0) PC1(ska.y, mk##S##a.y, 1) \
    PC1(ska.z, mk##S##a.z, 2) PC1(ska.w, mk##S##a.w, 3) \
    PC1(skc.x, mk##S##b.x, 4) PC1(skc.y, mk##S##b.y, 5) \
    PC1(skc.z, mk##S##b.z, 6) PC1(skc.w, mk##S##b.w, 7) \
    *(bf16x8*)&P[BUF][ip][jc * 8] = vv; }

// One phase: PCOMP(kp+1) consumes slot SC (issued 3 phases ago, oldest vmem ->
// compiler waits only those); 16 Ut loads; ISSUE slot SI for kp+4 (newest ->
// MFMA's Ut wait leaves it outstanding); 4 LDS A-frags; 32 MFMAs; fence barrier.
#define PHASE(SC, SI, KP) { \
    const int kp = (KP); \
    if (kp + 1 < 32) PCOMP(SC, (kp + 1) & 1, kp + 1) \
    bf16x8 bvA[8], bvB[8]; \
    _Pragma("unroll") \
    for (int n = 0; n < 8; ++n) { \
        const bf16x8* up = (const bf16x8*)(Ut + (size_t)(dw + 16 * n + lr) * 2048 + kp * 64 + 8 * lg); \
        bvA[n] = up[0]; bvB[n] = up[4]; \
    } \
    if (kp + 4 < 32) ISSUE(SI, kp + 4) \
    { \
        bf16x8 af0a = *(const bf16x8*)&P[kp & 1][lr][8 * lg]; \
        bf16x8 af0b = *(const bf16x8*)&P[kp & 1][lr][32 + 8 * lg]; \
        bf16x8 af1a = *(const bf16x8*)&P[kp & 1][16 + lr][8 * lg]; \
        bf16x8 af1b = *(const bf16x8*)&P[kp & 1][16 + lr][32 + 8 * lg]; \
        _Pragma("unroll") \
        for (int n = 0; n < 8; ++n) { \
            acc[0][n] = __builtin_amdgcn_mfma_f32_16x16x32_bf16(af0a, bvA[n], acc[0][n], 0, 0, 0); \
            acc[0][n] = __builtin_amdgcn_mfma_f32_16x16x32_bf16(af0b, bvB[n], acc[0][n], 0, 0, 0); \
            acc[1][n] = __builtin_amdgcn_mfma_f32_16x16x32_bf16(af1a, bvA[n], acc[1][n], 0, 0, 0); \
            acc[1][n] = __builtin_amdgcn_mfma_f32_16x16x32_bf16(af1b, bvB[n], acc[1][n], 0, 0, 0); \
        } \
    } \
    BAR }

__global__ __launch_bounds__(256, 2) void k_attn(const float* __restrict__ mask,
                                                 const float* __restrict__ b_out,
                                                 char* __restrict__ wsb,
                                                 float* __restrict__ out) {
    __shared__ unsigned short P[2][32][72];
    __shared__ float sk_lds[2048];
    __shared__ float sqs[32], rinvs[32], bcbo[512];
    __shared__ float psums[32][8];
    const int t = threadIdx.x;
    const int bid = blockIdx.x;
    const int b = bid & 7, i0 = (bid >> 3) * 32;      // b -> XCD; Ut[b] L2-resident
    const float* wsf = (const float*)(wsb + FP_OFF);
    const unsigned short* Ut = (const unsigned short*)(wsb + UT_OFF) + (size_t)b * 512 * 2048;
    const int ip = t >> 3, jc = t & 7;                // P-compute coords
    const int l = t & 63, lr = l & 15, lg = l >> 4;
    const int dw = (t >> 6) * 128;                    // wave's 128-col d-slice
    const float* mrowp = mask + ((size_t)(b * C_ + i0 + ip)) * C_ + jc * 8;

    f32x4 mk0a, mk0b, mk1a, mk1b, mk2a, mk2b, mk3a, mk3b;
    ISSUE(0, 0) ISSUE(1, 1) ISSUE(2, 2) ISSUE(3, 3)

    {   // stage sk row, sq, bias
        const float* skb = wsf + SKP_F + b * C_;
        *(float4*)&sk_lds[t * 8] = *(const float4*)(skb + t * 8);
        *(float4*)&sk_lds[t * 8 + 4] = *(const float4*)(skb + t * 8 + 4);
        if (t < 32) sqs[t] = wsf[SQP_F + b * C_ + i0 + t];
        bcbo[t] = wsf[BCOMB_F + t] + b_out[t];
        bcbo[t + 256] = wsf[BCOMB_F + t + 256] + b_out[t + 256];
    }
    __syncthreads();
    const float sqv = sqs[ip];
    float psum = 0.f;
    f32x4 acc[2][8];
#pragma unroll
    for (int m = 0; m < 2; ++m)
#pragma unroll
        for (int n = 0; n < 8; ++n) acc[m][n] = (f32x4){0.f, 0.f, 0.f, 0.f};

    PCOMP(0, 0, 0)
    BAR

    for (int o = 0; o < 8; ++o) {
        const int kt = o * 4;
        PHASE(1, 0, kt)
        PHASE(2, 1, kt + 1)
        PHASE(3, 2, kt + 2)
        PHASE(0, 3, kt + 3)
    }

    psums[ip][jc] = psum;
    __syncthreads();
    if (t < 32) {
        float4 pa = *(const float4*)&psums[t][0];
        float4 pb = *(const float4*)&psums[t][4];
        rinvs[t] = 1.0f / (pa.x + pa.y + pa.z + pa.w + pb.x + pb.y + pb.z + pb.w);
    }
    __syncthreads();
#pragma unroll
    for (int m = 0; m < 2; ++m) {
#pragma unroll
        for (int r = 0; r < 4; ++r) {
            const int irow = 16 * m + lg * 4 + r;
            const float rv = rinvs[irow];
            float* orow = out + ((size_t)(b * C_ + i0 + irow)) * DIM_ + dw;
#pragma unroll
            for (int n = 0; n < 8; ++n)
                orow[16 * n + lr] = acc[m][n][r] * rv + bcbo[dw + 16 * n + lr];
        }
    }
}

extern "C" void kernel_launch(void* const* d_in, const int* in_sizes, int n_in,
                              void* d_out, int out_size, void* d_ws, size_t ws_size,
                              hipStream_t stream) {
    const float* features = (const float*)d_in[0];
    const float* mask     = (const float*)d_in[1];
    const float* W_w      = (const float*)d_in[2];
    const float* b_w      = (const float*)d_in[3];
    const float* a_score  = (const float*)d_in[4];
    const float* b_score  = (const float*)d_in[5];
    const float* W_out    = (const float*)d_in[6];
    const float* b_out    = (const float*)d_in[7];
    float* out = (float*)d_out;
    char* wsb  = (char*)d_ws;
    float* wsf = (float*)(wsb + FP_OFF);

    k_prep_wqk<<<128, 256, 0, stream>>>(W_w, a_score, wsf);
    k_prep_cqk<<<1, 512, 0, stream>>>(b_w, a_score, b_score, wsf);
    k_wt<<<256, 256, 0, stream>>>(W_w, W_out, b_w, wsb, wsf);
    k_sqsk<<<4096, 256, 0, stream>>>(features, wsf);
    k_ut<<<512, 256, 0, stream>>>(features, wsb);
    k_attn<<<512, 256, 0, stream>>>(mask, b_out, wsb, out);
}